// Round 6
// baseline (476.681 us; speedup 1.0000x reference)
//
#include <hip/hip_runtime.h>
#include <math.h>

#define DEV __device__ __forceinline__

typedef short bf8 __attribute__((ext_vector_type(8)));   // 8 bf16 raw bits (4 VGPRs)
typedef float f32x4 __attribute__((ext_vector_type(4)));

#define TOK 10832

DEV unsigned short f2bf(float f) {
  union { float f; unsigned u; } x; x.f = f;
  unsigned r = x.u + 0x7fffu + ((x.u >> 16) & 1u);
  return (unsigned short)(r >> 16);
}
DEV float bf2f(unsigned short h) {
  union { unsigned u; float f; } x; x.u = ((unsigned)h) << 16; return x.f;
}
DEV unsigned cvtpk(float lo, float hi) {
  unsigned r;
  asm("v_cvt_pk_bf16_f32 %0, %1, %2" : "=v"(r) : "v"(lo), "v"(hi));
  return r;
}
DEV void decode_row(int row, int& s, int& b, int& p) {
  if (row < 4800)      { s = 0; b = row / 300; p = row - b * 300; }
  else if (row < 9600) { s = 1; int r = row - 4800; b = r / 300; p = r - b * 300; }
  else                 { s = 2; int r = row - 9600; b = r / 77;  p = r - b * 77; }
}
DEV f32x4 MFMA(bf8 a, bf8 b, f32x4 c) {
  return __builtin_amdgcn_mfma_f32_16x16x32_bf16(a, b, c, 0, 0, 0);
}
DEV void gld16(const unsigned short* g, unsigned short* l) {
  __builtin_amdgcn_global_load_lds((const __attribute__((address_space(1))) unsigned int*)g,
                                   (__attribute__((address_space(3))) unsigned int*)l,
                                   16, 0, 0);
}
DEV void vmdrain() { asm volatile("s_waitcnt vmcnt(0)" ::: "memory"); }
// counted-vmcnt barrier: own stage(t) landed + own LDS reads drained, then block barrier.
// Keeps newer staging loads (<= N outstanding) alive ACROSS the barrier (T4).
DEV void pipe_bar4() {
  asm volatile("s_waitcnt vmcnt(4) lgkmcnt(0)" ::: "memory");
  __builtin_amdgcn_s_barrier();
  __builtin_amdgcn_sched_barrier(0);
}
DEV void pipe_bar0() {
  asm volatile("s_waitcnt vmcnt(0) lgkmcnt(0)" ::: "memory");
  __builtin_amdgcn_s_barrier();
  __builtin_amdgcn_sched_barrier(0);
}

// ---------------- merged prep: weight transposes + padzero + rope + ada1 ------
// block ranges: [0,2304) Wqkv tr, [2304,3072) Wo tr, [3072,9216) Wff1 tr,
// [9216,12288) Wff2 tr, [12288,12416) padzero, [12416,12454) rope tab,
// [12454,12742) ada1 split-K.
DEV void tr32(const float* __restrict__ src, unsigned short* __restrict__ dst,
              int R, int C, int cx, int cy, int tid, float* sh) {
  int tx = tid & 31, ty = tid >> 5;
  int c0 = cx * 32, r0 = cy * 32;
  #pragma unroll
  for (int i = ty; i < 32; i += 8) sh[i * 33 + tx] = src[(long)(r0 + i) * C + c0 + tx];
  __syncthreads();
  #pragma unroll
  for (int i = ty; i < 32; i += 8) dst[(long)(c0 + i) * R + r0 + tx] = f2bf(sh[tx * 33 + i]);
}

__global__ __launch_bounds__(256) void k_prep(
    const float* __restrict__ Wqkv, const float* __restrict__ Wo,
    const float* __restrict__ Wff1, const float* __restrict__ Wff2,
    unsigned short* __restrict__ wqkvT, unsigned short* __restrict__ woT,
    unsigned short* __restrict__ wff1T, unsigned short* __restrict__ wff2T,
    unsigned short* __restrict__ qb, unsigned short* __restrict__ kb,
    unsigned short* __restrict__ vtb,
    float* __restrict__ rc, float* __restrict__ rs, float* __restrict__ rsc,
    const float* __restrict__ temb, const float* __restrict__ Wada,
    float* __restrict__ part) {
  __shared__ float sh[32 * 33];
  int i = blockIdx.x, tid = threadIdx.x;
  if (i < 2304) {
    int z = i >> 8, r = i & 255;
    tr32(Wqkv + (long)z * 262144, wqkvT + (long)z * 262144, 512, 512, r & 15, r >> 4, tid, sh);
  } else if (i < 3072) {
    int j = i - 2304; int z = j >> 8, r = j & 255;
    tr32(Wo + (long)z * 262144, woT + (long)z * 262144, 512, 512, r & 15, r >> 4, tid, sh);
  } else if (i < 9216) {
    int j = i - 3072; int z = j >> 11, r = j & 2047;
    tr32(Wff1 + (long)z * 2097152, wff1T + (long)z * 2097152, 512, 4096, r & 127, r >> 7, tid, sh);
  } else if (i < 12288) {
    int j = i - 9216; int z = j >> 10, r = j & 1023;
    tr32(Wff2 + (long)z * 1048576, wff2T + (long)z * 1048576, 2048, 512, r & 15, r >> 4, tid, sh);
  } else if (i < 12416) {
    int bh = i - 12288;
    for (int q = tid; q < 27 * 64; q += 256) {
      int r = 677 + (q >> 6), c = q & 63;
      long idx = ((long)bh * 704 + r) * 64 + c;
      qb[idx] = 0; kb[idx] = 0;
    }
    for (int q = tid; q < 64 * 27; q += 256) {
      int r = q / 27, c = 677 + (q - r * 27);
      vtb[((long)bh * 64 + r) * 704 + c] = 0;
    }
  } else if (i < 12454) {
    int q = (i - 12416) * 256 + tid;
    if (q < 300 * 32) {
      int p = q >> 5, f = q & 31;
      float inv = powf(10000.f, -(2.f * f) / 64.f);
      float ang = (float)p * inv;
      float base = (2.f * f + 25.6f) / 89.6f;
      float pw = (float)(p - 150) * (1.f / 512.f);
      rc[q] = cosf(ang);
      rs[q] = sinf(ang);
      rsc[q] = powf(base, pw);
    }
  } else {
    int j = i - 12454;
    int ex = j % 12, rest = j / 12, s = rest % 3, kc = rest / 3;
    int d0 = kc * 64;
    for (int q = tid; q < 16 * 64; q += 256) {
      int b = q >> 6, d = q & 63;
      float v = temb[b * 512 + d0 + d];
      sh[(b << 6) + d] = v / (1.f + __expf(-v));
    }
    __syncthreads();
    int e = ex * 256 + tid;
    float acc[16];
    #pragma unroll
    for (int b = 0; b < 16; b++) acc[b] = 0.f;
    const float* wp = Wada + (long)s * 512 * 3072 + (long)d0 * 3072 + e;
    for (int d = 0; d < 64; d++) {
      float wv = wp[(long)d * 3072];
      #pragma unroll
      for (int b = 0; b < 16; b++) acc[b] += sh[(b << 6) + d] * wv;
    }
    float* pp = part + (((long)kc * 3 + s) * 16) * 3072 + e;
    #pragma unroll
    for (int b = 0; b < 16; b++) pp[(long)b * 3072] = acc[b];
  }
}

// ---------------- ada stage 2: reduce 8 partials + bias -----------------------
__global__ __launch_bounds__(256) void k_ada2(const float* __restrict__ part,
    const float* __restrict__ bada, float* __restrict__ ada) {
  int idx = blockIdx.x * 256 + threadIdx.x;      // over 3*16*3072
  int e = idx % 3072, sb = idx / 3072, s = sb >> 4;
  float a = bada[s * 3072 + e];
  #pragma unroll
  for (int kc = 0; kc < 8; kc++) a += part[((long)kc * 48 + sb) * 3072 + e];
  ada[idx] = a;
}

// ---------------- LayerNorm + AdaLN modulate -> bf16 rows ---------------------
__global__ __launch_bounds__(256) void k_lnmod(const float* __restrict__ xp,
    const float* __restrict__ sp, const float* __restrict__ tp,
    const float* __restrict__ hbuf, const float* __restrict__ ada,
    unsigned short* __restrict__ outp, int chunk) {
  int row = blockIdx.x;
  int s, b, p; decode_row(row, s, b, p);
  const float* in;
  if (hbuf) in = hbuf + (long)row * 512;
  else {
    const float* basep = (s == 0) ? xp : (s == 1) ? sp : tp;
    int len = (s == 2) ? 77 : 300;
    in = basep + ((long)b * len + p) * 512;
  }
  int t = threadIdx.x;
  float v0 = in[t], v1 = in[t + 256];
  float s1 = v0 + v1, s2 = v0 * v0 + v1 * v1;
  #pragma unroll
  for (int d = 32; d; d >>= 1) { s1 += __shfl_xor(s1, d); s2 += __shfl_xor(s2, d); }
  __shared__ float r1[4], r2[4];
  int wid = t >> 6, lane = t & 63;
  if (lane == 0) { r1[wid] = s1; r2[wid] = s2; }
  __syncthreads();
  float S = r1[0] + r1[1] + r1[2] + r1[3];
  float Q = r2[0] + r2[1] + r2[2] + r2[3];
  float mean = S * (1.f / 512.f);
  float var = Q * (1.f / 512.f) - mean * mean;
  float rstd = rsqrtf(var + 1e-6f);
  const float* ap = ada + ((long)s * 16 + b) * 3072 + chunk * 512;
  float sh0 = ap[t], sh1 = ap[t + 256];
  float sc0 = ap[512 + t], sc1 = ap[512 + t + 256];
  long ob = (long)row * 512;
  outp[ob + t]       = f2bf((v0 - mean) * rstd * (1.f + sc0) + sh0);
  outp[ob + t + 256] = f2bf((v1 - mean) * rstd * (1.f + sc1) + sh1);
}

// ---------------- 128x128 MFMA GEMM, triple-buffered counted-vmcnt pipeline ---
template <int EPI>
__global__ __launch_bounds__(256) void k_gemm128(const unsigned short* __restrict__ A,
    const unsigned short* __restrict__ Wt, const float* __restrict__ bias,
    float* __restrict__ outF, unsigned short* __restrict__ outB,
    const float* __restrict__ hread, const float* __restrict__ ada,
    const float* __restrict__ xp, const float* __restrict__ sp, const float* __restrict__ tp,
    int K, int N) {
  int s = blockIdx.z;
  int mt = blockIdx.y;
  int Mtiles = (s == 2) ? 10 : 38;
  if (mt >= Mtiles) return;
  int Ms = (s == 2) ? 1232 : 4800;
  int rowbase = s * 4800;
  int m0 = mt * 128, n0 = blockIdx.x * 128;
  __shared__ unsigned short As[3][4096];
  __shared__ unsigned short Bs[3][4096];
  int tid = threadIdx.x;
  int w = tid >> 6, lane = tid & 63;
  int wr = w >> 1, wc = w & 1;
  int l16 = lane & 15, lg = lane >> 4;
  const unsigned short* Ag = A + (long)rowbase * K;
  const unsigned short* Bg = Wt + (long)s * N * K;
  int lrow = lane >> 2, lcol = (lane & 3) * 8;
  int ar[2], br[2];
  #pragma unroll
  for (int rnd = 0; rnd < 2; rnd++) {
    int rr = (w * 2 + rnd) * 16 + lrow;
    int a_ = m0 + rr; if (a_ >= Ms) a_ = Ms - 1;
    ar[rnd] = a_;
    br[rnd] = n0 + rr;
  }
  auto stage = [&](int kt, int bufi) {
    #pragma unroll
    for (int rnd = 0; rnd < 2; rnd++) {
      gld16(Ag + (long)ar[rnd] * K + kt + lcol, &As[bufi][(w * 2 + rnd) * 512]);
      gld16(Bg + (long)br[rnd] * K + kt + lcol, &Bs[bufi][(w * 2 + rnd) * 512]);
    }
  };
  f32x4 acc[4][4];
  #pragma unroll
  for (int i = 0; i < 4; i++)
    #pragma unroll
    for (int j = 0; j < 4; j++) acc[i][j] = (f32x4){0.f, 0.f, 0.f, 0.f};
  int nt = K >> 5;
  stage(0, 0);
  stage(32, 1);
  int bi = 0;
  for (int t = 0; t < nt; ++t) {
    if (t == nt - 1) pipe_bar0(); else pipe_bar4();
    if (t + 2 < nt) {
      int b2 = bi + 2; if (b2 >= 3) b2 -= 3;
      stage((t + 2) << 5, b2);
    }
    bf8 af[4], bv[4];
    #pragma unroll
    for (int i = 0; i < 4; i++) {
      af[i] = *(const bf8*)&As[bi][(wr * 64 + i * 16 + l16) * 32 + lg * 8];
      bv[i] = *(const bf8*)&Bs[bi][(wc * 64 + i * 16 + l16) * 32 + lg * 8];
    }
    #pragma unroll
    for (int i = 0; i < 4; i++)
      #pragma unroll
      for (int j = 0; j < 4; j++)
        acc[i][j] = MFMA(af[i], bv[j], acc[i][j]);
    bi = (bi + 1 == 3) ? 0 : bi + 1;
  }
  #pragma unroll
  for (int i = 0; i < 4; i++) {
    #pragma unroll
    for (int r = 0; r < 4; r++) {
      int rloc = m0 + wr * 64 + i * 16 + lg * 4 + r;
      if (rloc >= Ms) continue;
      int grow = rowbase + rloc;
      int b, p;
      if (s == 2) { b = rloc / 77;  p = rloc - b * 77; }
      else        { b = rloc / 300; p = rloc - b * 300; }
      #pragma unroll
      for (int j = 0; j < 4; j++) {
        int col = n0 + wc * 64 + j * 16 + l16;
        float v = acc[i][j][r] + bias[s * N + col];
        if constexpr (EPI == 0) {
          outB[(long)grow * 1536 + col] = f2bf(v);
        } else if constexpr (EPI == 1) {
          const float* basep = (s == 0) ? xp : (s == 1) ? sp : tp;
          int len = (s == 2) ? 77 : 300;
          float iv = basep[((long)b * len + p) * 512 + col];
          float ga = ada[((long)s * 16 + b) * 3072 + 1024 + col];
          outF[(long)grow * 512 + col] = iv + ga * v;
        } else {
          float hv = hread[(long)grow * 512 + col];
          float gm = ada[((long)s * 16 + b) * 3072 + 2560 + col];
          int l = ((s == 0) ? 377 : (s == 1) ? 77 : 0) + p;
          outF[((long)b * 677 + l) * 512 + col] = hv + gm * v;
        }
      }
    }
  }
}

// ---------------- FF1 GEMM + fused GEGLU, same pipelined structure ------------
__global__ __launch_bounds__(256) void k_geglu128(const unsigned short* __restrict__ A,
    const unsigned short* __restrict__ Wt, const float* __restrict__ bias,
    unsigned short* __restrict__ gout) {
  int s = blockIdx.z;
  int mt = blockIdx.y;
  int Mtiles = (s == 2) ? 10 : 38;
  if (mt >= Mtiles) return;
  int Ms = (s == 2) ? 1232 : 4800;
  int rowbase = s * 4800;
  int m0 = mt * 128, n0 = blockIdx.x * 64;
  __shared__ unsigned short As[3][4096];
  __shared__ unsigned short Bl[3][2048];
  __shared__ unsigned short Bg[3][2048];
  int tid = threadIdx.x;
  int w = tid >> 6, lane = tid & 63;
  int l16 = lane & 15, lg = lane >> 4;
  const unsigned short* Ag = A + (long)rowbase * 512;
  const unsigned short* Ws = Wt + (long)s * 4096 * 512;
  int lrow = lane >> 2, lcol = (lane & 3) * 8;
  int ar[2];
  #pragma unroll
  for (int rnd = 0; rnd < 2; rnd++) {
    int a_ = m0 + (w * 2 + rnd) * 16 + lrow; if (a_ >= Ms) a_ = Ms - 1;
    ar[rnd] = a_;
  }
  int blr = n0 + w * 16 + lrow;
  int bgr = 2048 + n0 + w * 16 + lrow;
  auto stage = [&](int kt, int bufi) {
    #pragma unroll
    for (int rnd = 0; rnd < 2; rnd++)
      gld16(Ag + (long)ar[rnd] * 512 + kt + lcol, &As[bufi][(w * 2 + rnd) * 512]);
    gld16(Ws + (long)blr * 512 + kt + lcol, &Bl[bufi][w * 512]);
    gld16(Ws + (long)bgr * 512 + kt + lcol, &Bg[bufi][w * 512]);
  };
  f32x4 accl[2][4], accg[2][4];
  #pragma unroll
  for (int i = 0; i < 2; i++)
    #pragma unroll
    for (int j = 0; j < 4; j++) {
      accl[i][j] = (f32x4){0.f, 0.f, 0.f, 0.f};
      accg[i][j] = (f32x4){0.f, 0.f, 0.f, 0.f};
    }
  stage(0, 0);
  stage(32, 1);
  int bi = 0;
  for (int t = 0; t < 16; ++t) {
    if (t == 15) pipe_bar0(); else pipe_bar4();
    if (t + 2 < 16) {
      int b2 = bi + 2; if (b2 >= 3) b2 -= 3;
      stage((t + 2) << 5, b2);
    }
    bf8 af[2], bl[4], bg[4];
    #pragma unroll
    for (int i = 0; i < 2; i++)
      af[i] = *(const bf8*)&As[bi][(w * 32 + i * 16 + l16) * 32 + lg * 8];
    #pragma unroll
    for (int j = 0; j < 4; j++) {
      bl[j] = *(const bf8*)&Bl[bi][(j * 16 + l16) * 32 + lg * 8];
      bg[j] = *(const bf8*)&Bg[bi][(j * 16 + l16) * 32 + lg * 8];
    }
    #pragma unroll
    for (int i = 0; i < 2; i++)
      #pragma unroll
      for (int j = 0; j < 4; j++) {
        accl[i][j] = MFMA(af[i], bl[j], accl[i][j]);
        accg[i][j] = MFMA(af[i], bg[j], accg[i][j]);
      }
    bi = (bi + 1 == 3) ? 0 : bi + 1;
  }
  #pragma unroll
  for (int i = 0; i < 2; i++) {
    #pragma unroll
    for (int r = 0; r < 4; r++) {
      int rloc = m0 + w * 32 + i * 16 + lg * 4 + r;
      if (rloc >= Ms) continue;
      int grow = rowbase + rloc;
      #pragma unroll
      for (int j = 0; j < 4; j++) {
        int col = n0 + j * 16 + l16;
        float lv = accl[i][j][r] + bias[s * 4096 + col];
        float gv = accg[i][j][r] + bias[s * 4096 + 2048 + col];
        float g  = lv * 0.5f * gv * (1.f + erff(gv * 0.70710678118654752f));
        gout[(long)grow * 2048 + col] = f2bf(g);
      }
    }
  }
}

// ---------------- RMS-norm + rope/pos-embed + attention layout ----------------
__global__ __launch_bounds__(256) void k_rmsrope(const unsigned short* __restrict__ qkv,
    const float* __restrict__ gqk, const float* __restrict__ posq, const float* __restrict__ posk,
    const float* __restrict__ rcos, const float* __restrict__ rsin, const float* __restrict__ rscl,
    unsigned short* __restrict__ qb, unsigned short* __restrict__ kb,
    unsigned short* __restrict__ vtb) {
  int gw = (blockIdx.x * 256 + threadIdx.x) >> 6;
  int lane = threadIdx.x & 63;
  int token = gw >> 3, h = gw & 7;
  if (token >= TOK) return;
  int s, b, p; decode_row(token, s, b, p);
  long base = (long)token * 1536 + h * 64 + lane;
  float q = bf2f(qkv[base]);
  float k = bf2f(qkv[base + 512]);
  float v = bf2f(qkv[base + 1024]);
  float sq = q * q, sk = k * k;
  #pragma unroll
  for (int d = 32; d; d >>= 1) { sq += __shfl_xor(sq, d); sk += __shfl_xor(sk, d); }
  q *= rsqrtf(sq * (1.f / 64.f) + 1e-6f) * gqk[s * 128 + lane];
  k *= rsqrtf(sk * (1.f / 64.f) + 1e-6f) * gqk[s * 128 + 64 + lane];
  int l;
  if (s == 2) {
    l = p;
    q += posq[p * 64 + lane];
    k += posk[p * 64 + lane];
  } else {
    l = (s == 1 ? 77 : 377) + p;
    int pr = lane >> 1;
    float c = rcos[p * 32 + pr], sn = rsin[p * 32 + pr], sc = rscl[p * 32 + pr];
    float qo = __shfl_xor(q, 1), ko = __shfl_xor(k, 1);
    float sgn = (lane & 1) ? 1.f : -1.f;
    q = (q * c + sgn * qo * sn) * sc;
    k = (k * c + sgn * ko * sn) / sc;
  }
  long bh = (long)(b * 8 + h);
  long qi = (bh * 704 + l) * 64 + lane;
  qb[qi] = f2bf(q);
  kb[qi] = f2bf(k);
  vtb[(bh * 64 + lane) * 704 + l] = f2bf(v);
}

// ---------------- flash attention: LDS-staged K/V tiles, 8 waves/block --------
__global__ __launch_bounds__(512, 8) void k_attn(const unsigned short* __restrict__ qb,
    const unsigned short* __restrict__ kb, const unsigned short* __restrict__ vtb,
    const int* __restrict__ valid, unsigned short* __restrict__ ob) {
  __shared__ unsigned short Kb[2][4096];   // [64 rows][64 d] swizzled (8KB)
  __shared__ unsigned short Vb[2][4096];   // [64 d][64 keys] swizzled (8KB)
  __shared__ unsigned char maskv[704];
  int f0 = blockIdx.x;
  int fp = (f0 & 7) * 96 + (f0 >> 3);      // XCD-chunked bijective swizzle (768 = 8*96)
  int bh = fp / 6, qtile = fp - bh * 6;
  int b = bh >> 3, h = bh & 7;
  int tid = threadIdx.x;
  for (int i = tid; i < 704; i += 512)
    maskv[i] = (i < 677) ? (unsigned char)(valid[b * 677 + i] != 0) : (unsigned char)0;
  int w = tid >> 6, lane = tid & 63;
  int l16 = lane & 15, lg = lane >> 4;
  int qt = qtile * 128 + w * 16;
  int qrow = qt + l16;
  int qrc = qrow > 703 ? 703 : qrow;
  const unsigned short* qbase = qb + (long)bh * 704 * 64;
  const unsigned short* kbase = kb + (long)bh * 704 * 64;
  const unsigned short* vbase = vtb + (long)bh * 64 * 704;
  bf8 qf0 = *(const bf8*)(qbase + qrc * 64 + lg * 8);
  bf8 qf1 = *(const bf8*)(qbase + qrc * 64 + 32 + lg * 8);
  int scol = (((lane & 7) << 4) ^ ((lane >> 3) << 4)) >> 1;   // ushort units
  int srow = w * 8 + (lane >> 3);
  const unsigned short* ksrc = kbase + srow * 64 + scol;
  const unsigned short* vsrc = vbase + srow * 704 + scol;
  unsigned short* kd0 = &Kb[0][w * 512];
  unsigned short* kd1 = &Kb[1][w * 512];
  unsigned short* vd0 = &Vb[0][w * 512];
  unsigned short* vd1 = &Vb[1][w * 512];
  gld16(ksrc, kd0);
  gld16(vsrc, vd0);
  vmdrain();
  __syncthreads();
  int mq = maskv[qrc];
  int sw = (l16 & 7) << 4;
  float lsum = 0.f;
  f32x4 Oc[4];
  #pragma unroll
  for (int df = 0; df < 4; df++) Oc[df] = (f32x4){0.f, 0.f, 0.f, 0.f};
  union U { bf8 v; unsigned u[4]; uint2 d[2]; };
  int buf = 0;
  for (int t = 0; t < 11; t++) {
    if (t < 10) {
      int ktn = (t + 1) * 64;
      gld16(ksrc + ktn * 64, buf ? kd0 : kd1);
      gld16(vsrc + ktn, buf ? vd0 : vd1);
    }
    int kt = t * 64;
    const unsigned short* Kc = Kb[buf];
    const unsigned short* Vc = Vb[buf];
    float psum = 0.f;
    unsigned pk[4][2];
    #pragma unroll
    for (int f = 0; f < 4; f++) {
      int row = f * 16 + l16;
      f32x4 sa = (f32x4){0.f, 0.f, 0.f, 0.f};
      sa = MFMA(*(const bf8*)&Kc[(row * 128 + ((lg * 16) ^ sw)) >> 1], qf0, sa);
      sa = MFMA(*(const bf8*)&Kc[(row * 128 + ((lg * 16 + 64) ^ sw)) >> 1], qf1, sa);
      unsigned mw = *(const unsigned*)&maskv[kt + f * 16 + lg * 4];
      float pr[4];
      #pragma unroll
      for (int r = 0; r < 4; r++) {
        int key = kt + f * 16 + lg * 4 + r;
        bool ok = ((mq & (mw >> (8 * r))) & 1) || (key == qrow);
        float sv = ok ? fmaf(sa[r], 0.125f, -20.f) : -1e30f;
        float pv = __expf(sv);
        pr[r] = pv;
        psum += pv;
      }
      pk[f][0] = cvtpk(pr[0], pr[1]);
      pk[f][1] = cvtpk(pr[2], pr[3]);
    }
    psum += __shfl_xor(psum, 16);
    psum += __shfl_xor(psum, 32);
    lsum += psum;
    #pragma unroll
    for (int c = 0; c < 2; c++) {
      U pu;
      pu.u[0] = pk[2 * c][0]; pu.u[1] = pk[2 * c][1];
      pu.u[2] = pk[2 * c + 1][0]; pu.u[3] = pk[2 * c + 1][1];
      #pragma unroll
      for (int df = 0; df < 4; df++) {
        int row = df * 16 + l16;
        U vu;
        vu.d[0] = *(const uint2*)&Vc[(row * 128 + ((c * 64 + lg * 8) ^ sw)) >> 1];
        vu.d[1] = *(const uint2*)&Vc[(row * 128 + ((c * 64 + lg * 8 + 32) ^ sw)) >> 1];
        Oc[df] = MFMA(vu.v, pu.v, Oc[df]);
      }
    }
    vmdrain();
    __syncthreads();
    buf ^= 1;
  }
  if (qrow < 677) {
    float inv = 1.f / fmaxf(lsum, 1e-30f);
    int l = qrow;
    int orow = (l < 77) ? 9600 + b * 77 + l
             : (l < 377) ? 4800 + b * 300 + (l - 77)
                         : b * 300 + (l - 377);
    unsigned short* op = ob + (long)orow * 512 + h * 64;
    #pragma unroll
    for (int df = 0; df < 4; df++) {
      uint2 st;
      st.x = cvtpk(Oc[df][0] * inv, Oc[df][1] * inv);
      st.y = cvtpk(Oc[df][2] * inv, Oc[df][3] * inv);
      *(uint2*)(op + df * 16 + lg * 4) = st;
    }
  }
}

// -----------------------------------------------------------------------------
extern "C" void kernel_launch(void* const* d_in, const int* in_sizes, int n_in,
                              void* d_out, int out_size, void* d_ws, size_t ws_size,
                              hipStream_t stream) {
  const float* xp   = (const float*)d_in[0];
  const float* sp   = (const float*)d_in[1];
  const float* tp   = (const float*)d_in[2];
  const float* temb = (const float*)d_in[3];
  const float* Wqkv = (const float*)d_in[4];
  const float* bqkv = (const float*)d_in[5];
  const float* Wo   = (const float*)d_in[6];
  const float* bo   = (const float*)d_in[7];
  const float* gqk  = (const float*)d_in[8];
  const float* Wada = (const float*)d_in[9];
  const float* bada = (const float*)d_in[10];
  const float* Wff1 = (const float*)d_in[11];
  const float* bff1 = (const float*)d_in[12];
  const float* Wff2 = (const float*)d_in[13];
  const float* bff2 = (const float*)d_in[14];
  const float* posq = (const float*)d_in[15];
  const float* posk = (const float*)d_in[16];
  const int*   valid= (const int*)d_in[17];
  float* out = (float*)d_out;

  char* w = (char*)d_ws;
  size_t off = 0;
  auto take = [&](size_t bytes) -> char* {
    char* p = w + off;
    off = (off + bytes + 255) & ~(size_t)255;
    return p;
  };
  unsigned short* wqkvT = (unsigned short*)take(3UL * 1536 * 512 * 2);
  unsigned short* woT   = (unsigned short*)take(3UL * 512 * 512 * 2);
  unsigned short* wff1T = (unsigned short*)take(3UL * 4096 * 512 * 2);
  unsigned short* wff2T = (unsigned short*)take(3UL * 512 * 2048 * 2);
  float*          adab  = (float*)take(3UL * 16 * 3072 * 4);
  float*          adap  = (float*)take(8UL * 3 * 16 * 3072 * 4);
  float*          rcosb = (float*)take(300UL * 32 * 4);
  float*          rsinb = (float*)take(300UL * 32 * 4);
  float*          rsclb = (float*)take(300UL * 32 * 4);
  unsigned short* nbuf  = (unsigned short*)take((size_t)TOK * 512 * 2);
  unsigned short* qkvb  = (unsigned short*)take((size_t)TOK * 1536 * 2);
  unsigned short* qbf   = (unsigned short*)take(16UL * 8 * 704 * 64 * 2);
  unsigned short* kbf   = (unsigned short*)take(16UL * 8 * 704 * 64 * 2);
  unsigned short* vtb   = (unsigned short*)take(16UL * 8 * 64 * 704 * 2);
  unsigned short* obuf  = (unsigned short*)take((size_t)TOK * 512 * 2);
  float*          hb    = (float*)take((size_t)TOK * 512 * 4);
  unsigned short* n2b   = (unsigned short*)take((size_t)TOK * 512 * 2);
  unsigned short* gbuf  = (unsigned short*)take((size_t)TOK * 2048 * 2);
  (void)ws_size; (void)in_sizes; (void)n_in; (void)out_size;

  k_prep<<<12742, 256, 0, stream>>>(Wqkv, Wo, Wff1, Wff2, wqkvT, woT, wff1T, wff2T,
                                    qbf, kbf, vtb, rcosb, rsinb, rsclb, temb, Wada, adap);
  k_ada2<<<576, 256, 0, stream>>>(adap, bada, adab);
  k_lnmod<<<TOK, 256, 0, stream>>>(xp, sp, tp, nullptr, adab, nbuf, 0);
  k_gemm128<0><<<dim3(12, 38, 3), 256, 0, stream>>>(nbuf, wqkvT, bqkv, nullptr, qkvb, nullptr,
                                                    adab, xp, sp, tp, 512, 1536);
  k_rmsrope<<<21664, 256, 0, stream>>>(qkvb, gqk, posq, posk, rcosb, rsinb, rsclb, qbf, kbf, vtb);
  k_attn<<<768, 512, 0, stream>>>(qbf, kbf, vtb, valid, obuf);
  k_gemm128<1><<<dim3(4, 38, 3), 256, 0, stream>>>(obuf, woT, bo, hb, nullptr, nullptr,
                                                   adab, xp, sp, tp, 512, 512);
  k_lnmod<<<TOK, 256, 0, stream>>>(xp, sp, tp, hb, adab, n2b, 3);
  k_geglu128<<<dim3(32, 38, 3), 256, 0, stream>>>(n2b, wff1T, bff1, gbuf);
  k_gemm128<2><<<dim3(4, 38, 3), 256, 0, stream>>>(gbuf, wff2T, bff2, out, nullptr, hb,
                                                   adab, xp, sp, tp, 2048, 512);
}